// Round 1
// 135.109 us; speedup vs baseline: 1.7569x; 1.7569x over previous
//
#include <hip/hip_runtime.h>

#define DDIM 64
#define MAXNS 2048          // max slices (nodes/256) handled by the new path
#define PART_TPB 256
#define PART_EPT 16
#define PART_EPB (PART_TPB * PART_EPT)   // 4096 edges per block

__device__ __forceinline__ float atomAddF(float* p, float v) {
    return unsafeAtomicAdd(p, v);   // HW global_atomic_add_f32 on gfx950
}

// ================= NEW CSR BUILD: two-level counting sort by dst>>8 =================
// Rationale: old fill_kernel did 4B scattered stores over a 4.8MB range ->
// ~16x write amplification (85MB WRITE_SIZE, 96us). Partitioning by slice
// keeps all scattered stores inside L2-resident windows.

// Pass 1: per-slice edge counts (LDS-aggregated histogram)
__global__ void slice_count_kernel(const int* __restrict__ dst, int* __restrict__ sliceCnt,
                                   int nE, int NS) {
    __shared__ int lh[MAXNS];
    int t = threadIdx.x;
    int blockBase = blockIdx.x * PART_EPB;
    for (int i = t; i < NS; i += PART_TPB) lh[i] = 0;
    __syncthreads();
    #pragma unroll
    for (int c = 0; c < 4; ++c) {
        int e0 = blockBase + (c * PART_TPB + t) * 4;
        if (e0 + 3 < nE) {
            int4 b = *(const int4*)(dst + e0);
            atomicAdd(&lh[b.x >> 8], 1); atomicAdd(&lh[b.y >> 8], 1);
            atomicAdd(&lh[b.z >> 8], 1); atomicAdd(&lh[b.w >> 8], 1);
        } else {
            for (int j = 0; j < 4; ++j) {
                int e = e0 + j;
                if (e < nE) atomicAdd(&lh[dst[e] >> 8], 1);
            }
        }
    }
    __syncthreads();
    for (int i = t; i < NS; i += PART_TPB)
        if (lh[i]) atomicAdd(&sliceCnt[i], lh[i]);
}

// Pass 2 (1 block): exclusive scan of slice counts -> sliceBase[] (persistent)
// and scnt[] reused as running cursors for partition. Fused Wp build.
__global__ void slice_scan_wp_kernel(int* __restrict__ scnt, int* __restrict__ sbase,
                                     int NS, int nE,
                                     const float* __restrict__ W, const float* __restrict__ lamda_p,
                                     const int* __restrict__ layer_p, float* __restrict__ Wp) {
    __shared__ int sdata[512];
    int t = threadIdx.x;
    int base = t * 4;
    int v[4];
    #pragma unroll
    for (int j = 0; j < 4; ++j) {
        int idx = base + j;
        v[j] = (idx < NS) ? scnt[idx] : 0;
    }
    int local = v[0] + v[1] + v[2] + v[3];
    sdata[t] = local;
    __syncthreads();
    for (int off = 1; off < 512; off <<= 1) {
        int y = (t >= off) ? sdata[t - off] : 0;
        __syncthreads();
        sdata[t] += y;
        __syncthreads();
    }
    int run = sdata[t] - local;
    #pragma unroll
    for (int j = 0; j < 4; ++j) {
        int idx = base + j;
        if (idx < NS) { sbase[idx] = run; scnt[idx] = run; }
        run += v[j];
    }
    if (t == 0) sbase[NS] = nE;

    float lam = lamda_p[0];
    int lb = layer_p[0];
    float layerf = (lb > 0 && lb < (1 << 23)) ? (float)lb : __int_as_float(lb);
    float beta = logf(lam / layerf + 1.0f);
    for (int i = t; i < DDIM * DDIM; i += 512) {
        int k = i >> 6, d = i & 63;
        float w = beta * W[i];
        if (k == d) w += (1.0f - beta);
        Wp[i] = w;
    }
}

// Pass 3: scatter packed (src<<8 | dstLow) into per-slice staging regions.
// Per-block LDS histogram -> ONE global atomicAdd per (block,slice) to reserve
// a contiguous run -> scattered stores confined to tiny contiguous runs.
__global__ void partition_kernel(const int* __restrict__ src, const int* __restrict__ dst,
                                 int* __restrict__ cursor, unsigned* __restrict__ staging,
                                 int nE, int NS) {
    __shared__ int lh[MAXNS];
    __shared__ int lbase[MAXNS];
    int t = threadIdx.x;
    int blockBase = blockIdx.x * PART_EPB;
    for (int i = t; i < NS; i += PART_TPB) lh[i] = 0;
    __syncthreads();

    int se[PART_EPT]; int de[PART_EPT];
    #pragma unroll
    for (int c = 0; c < 4; ++c) {
        int e0 = blockBase + (c * PART_TPB + t) * 4;
        if (e0 + 3 < nE) {
            int4 a = *(const int4*)(src + e0);
            int4 b = *(const int4*)(dst + e0);
            se[4*c+0] = a.x; se[4*c+1] = a.y; se[4*c+2] = a.z; se[4*c+3] = a.w;
            de[4*c+0] = b.x; de[4*c+1] = b.y; de[4*c+2] = b.z; de[4*c+3] = b.w;
        } else {
            #pragma unroll
            for (int j = 0; j < 4; ++j) {
                int e = e0 + j;
                se[4*c+j] = (e < nE) ? src[e] : 0;
                de[4*c+j] = (e < nE) ? dst[e] : -1;
            }
        }
    }
    #pragma unroll
    for (int k = 0; k < PART_EPT; ++k)
        if (de[k] >= 0) atomicAdd(&lh[de[k] >> 8], 1);
    __syncthreads();
    for (int i = t; i < NS; i += PART_TPB) {
        int c = lh[i];
        if (c) lbase[i] = atomicAdd(&cursor[i], c);
        lh[i] = 0;
    }
    __syncthreads();
    #pragma unroll
    for (int k = 0; k < PART_EPT; ++k) {
        int d = de[k];
        if (d >= 0) {
            int sl = d >> 8;
            int off = atomicAdd(&lh[sl], 1);
            staging[lbase[sl] + off] = ((unsigned)se[k] << 8) | (unsigned)(d & 255);
        }
    }
}

// Pass 4: one block per slice. Histogram 256 local nodes (== degI), LDS scan
// (== row_end), write normv, then scatter eidx inside an L2-resident ~12KB window.
__global__ void bin_fill_kernel(const unsigned* __restrict__ staging, const int* __restrict__ sbase,
                                int* __restrict__ degI, float* __restrict__ normv,
                                int* __restrict__ row_end, int* __restrict__ eidx, int nN) {
    __shared__ int cnt[256];
    __shared__ int pos[256];
    int s = blockIdx.x;
    int t = threadIdx.x;
    int b0 = sbase[s], b1 = sbase[s + 1];
    cnt[t] = 0;
    __syncthreads();
    for (int j = b0 + t; j < b1; j += 256) {
        unsigned p = staging[j];
        atomicAdd(&cnt[p & 255], 1);
    }
    __syncthreads();
    int c = cnt[t];
    pos[t] = c;
    __syncthreads();
    for (int off = 1; off < 256; off <<= 1) {
        int y = (t >= off) ? pos[t - off] : 0;
        __syncthreads();
        pos[t] += y;
        __syncthreads();
    }
    int inc = pos[t];
    int exc = inc - c;
    int node = (s << 8) + t;
    if (node < nN) {
        degI[node] = c;
        normv[node] = rsqrtf(fmaxf((float)c, 1.0f));
        row_end[node] = b0 + inc;
    }
    pos[t] = b0 + exc;          // per-thread own slot; becomes scatter cursor
    __syncthreads();
    for (int j = b0 + t; j < b1; j += 256) {
        unsigned p = staging[j];
        int q = atomicAdd(&pos[p & 255], 1);
        eidx[q] = (int)(p >> 8);
    }
}

// featS = feat * norm[node] (float4); block handles 16 nodes
__global__ void scale_kernel(const float4* __restrict__ feat4, const float* __restrict__ normv,
                             float4* __restrict__ featS4, int nN) {
    int b = blockIdx.x, t = threadIdx.x;
    int node = b * 16 + (t >> 4);
    int r = t & 15;
    if (node < nN) {
        float nv = normv[node];
        float4 v = feat4[(size_t)node * 16 + r];
        v.x *= nv; v.y *= nv; v.z *= nv; v.w *= nv;
        featS4[(size_t)node * 16 + r] = v;
    }
}

// ================= OLD CSR BUILD (fallback tier) =================

__global__ void deg_int_kernel(const int* __restrict__ dst, int* __restrict__ degI, int nE) {
    int i = blockIdx.x * blockDim.x + threadIdx.x;
    int base = i * 4;
    if (base + 3 < nE) {
        int4 d = *(const int4*)(dst + base);
        atomicAdd(&degI[d.x], 1); atomicAdd(&degI[d.y], 1);
        atomicAdd(&degI[d.z], 1); atomicAdd(&degI[d.w], 1);
    } else {
        for (int j = base; j < nE; ++j) atomicAdd(&degI[dst[j]], 1);
    }
}

#define SCAN_BLOCK 256
#define SCAN_CHUNK 1024

__global__ void scan1_kernel(const int* __restrict__ degI, int* __restrict__ row_start,
                             float* __restrict__ normv, int* __restrict__ blockSums, int nN) {
    __shared__ int sdata[SCAN_BLOCK];
    int t = threadIdx.x;
    int base = blockIdx.x * SCAN_CHUNK + t * 4;
    int v[4];
    #pragma unroll
    for (int j = 0; j < 4; ++j) {
        int idx = base + j;
        v[j] = (idx < nN) ? degI[idx] : 0;
    }
    int local = v[0] + v[1] + v[2] + v[3];
    sdata[t] = local;
    __syncthreads();
    for (int off = 1; off < SCAN_BLOCK; off <<= 1) {
        int y = (t >= off) ? sdata[t - off] : 0;
        __syncthreads();
        sdata[t] += y;
        __syncthreads();
    }
    int inc = sdata[t];
    int exc = inc - local;
    if (t == SCAN_BLOCK - 1) blockSums[blockIdx.x] = inc;
    int run = exc;
    #pragma unroll
    for (int j = 0; j < 4; ++j) {
        int idx = base + j;
        if (idx < nN) {
            row_start[idx] = run;
            normv[idx] = rsqrtf(fmaxf((float)v[j], 1.0f));
        }
        run += v[j];
    }
}

__global__ void scan2_wp_kernel(int* __restrict__ blockSums, int nb,
                                const float* __restrict__ W, const float* __restrict__ lamda_p,
                                const int* __restrict__ layer_p, float* __restrict__ Wp) {
    __shared__ int sdata[SCAN_BLOCK];
    int t = threadIdx.x;
    int v = (t < nb) ? blockSums[t] : 0;
    sdata[t] = v;
    __syncthreads();
    for (int off = 1; off < SCAN_BLOCK; off <<= 1) {
        int y = (t >= off) ? sdata[t - off] : 0;
        __syncthreads();
        sdata[t] += y;
        __syncthreads();
    }
    if (t < nb) blockSums[t] = sdata[t] - v;

    float lam = lamda_p[0];
    int lb = layer_p[0];
    float layerf = (lb > 0 && lb < (1 << 23)) ? (float)lb : __int_as_float(lb);
    float beta = logf(lam / layerf + 1.0f);
    for (int i = t; i < DDIM * DDIM; i += SCAN_BLOCK) {
        int k = i >> 6, d = i & 63;
        float w = beta * W[i];
        if (k == d) w += (1.0f - beta);
        Wp[i] = w;
    }
}

__global__ void scan3_scale_kernel(int* __restrict__ row_start, const int* __restrict__ blockSums,
                                   const float4* __restrict__ feat4, const float* __restrict__ normv,
                                   float4* __restrict__ featS4, int nN) {
    int b = blockIdx.x, t = threadIdx.x;
    int node = b * 16 + (t >> 4);
    int r = t & 15;
    if (node < nN) {
        float nv = normv[node];
        float4 v = feat4[(size_t)node * 16 + r];
        v.x *= nv; v.y *= nv; v.z *= nv; v.w *= nv;
        featS4[(size_t)node * 16 + r] = v;
    }
    if (t < 16) {
        int n2 = b * 16 + t;
        if (n2 < nN) row_start[n2] += blockSums[n2 >> 10];
    }
}

__global__ void scan3_kernel(int* __restrict__ row_start, const int* __restrict__ blockSums, int nN) {
    int i = blockIdx.x * blockDim.x + threadIdx.x;
    if (i < nN) row_start[i] += blockSums[i >> 10];
}

__global__ void fill_kernel(const int* __restrict__ src, const int* __restrict__ dst,
                            int* __restrict__ row_start, int* __restrict__ eidx, int nE) {
    int i = blockIdx.x * blockDim.x + threadIdx.x;
    int base = i * 4;
    if (base + 3 < nE) {
        int4 s = *(const int4*)(src + base);
        int4 d = *(const int4*)(dst + base);
        eidx[atomicAdd(&row_start[d.x], 1)] = s.x;
        eidx[atomicAdd(&row_start[d.y], 1)] = s.y;
        eidx[atomicAdd(&row_start[d.z], 1)] = s.z;
        eidx[atomicAdd(&row_start[d.w], 1)] = s.w;
    } else {
        for (int j = base; j < nE; ++j) {
            int tt = dst[j];
            int p = atomicAdd(&row_start[tt], 1);
            eidx[p] = src[j];
        }
    }
}

// ---------------- fused gather + epilogue (wave per node, 4x16 lane layout) ----------------
template<bool SCALED>
__global__ void gather_kernel(const float4* __restrict__ featv, const float4* __restrict__ feat04,
                              const float* __restrict__ normv, const int* __restrict__ degI,
                              const int* __restrict__ row_end, const int* __restrict__ eidx,
                              const float* __restrict__ Wp, const float* __restrict__ alpha_p,
                              float4* __restrict__ out4, int nN) {
    __shared__ float4 sW[DDIM * 16];   // 16 KiB, XOR-swizzled
    const float4* Wp4 = (const float4*)Wp;
    for (int i = threadIdx.x; i < DDIM * 16; i += blockDim.x) {
        sW[(i & ~15) | ((i & 15) ^ ((i >> 8) & 3))] = Wp4[i];
    }
    __syncthreads();

    int lane = threadIdx.x & 63;
    int w = threadIdx.x >> 6;
    int g = lane >> 4;
    int r = lane & 15;
    int n = blockIdx.x * 4 + w;
    if (n >= nN) return;

    int end = row_end[n];
    int deg = degI[n];
    int start = end - deg;

    float4 acc = make_float4(0.f, 0.f, 0.f, 0.f);

    for (int j0 = start; j0 < end; j0 += 64) {
        int m = end - j0; if (m > 64) m = 64;
        int sIdx = 0;
        float nv = 1.0f;
        if (lane < m) {
            sIdx = eidx[j0 + lane];
            if (!SCALED) nv = normv[sIdx];
        }
        int nt = (m + 3) >> 2;
        int t = 0;
        for (; t + 2 <= nt; t += 2) {
            int e0 = 4 * t + g, e1 = e0 + 4;
            int s0 = __shfl(sIdx, e0, 64);
            int s1 = __shfl(sIdx, e1, 64);
            float ns0 = SCALED ? 1.0f : __shfl(nv, e0, 64);
            float ns1 = SCALED ? 1.0f : __shfl(nv, e1, 64);
            float4 a = featv[(size_t)s0 * 16 + r];
            float4 b = featv[(size_t)s1 * 16 + r];
            float w0 = (e0 < m) ? ns0 : 0.0f;
            float w1 = (e1 < m) ? ns1 : 0.0f;
            acc.x = fmaf(a.x, w0, acc.x); acc.y = fmaf(a.y, w0, acc.y);
            acc.z = fmaf(a.z, w0, acc.z); acc.w = fmaf(a.w, w0, acc.w);
            acc.x = fmaf(b.x, w1, acc.x); acc.y = fmaf(b.y, w1, acc.y);
            acc.z = fmaf(b.z, w1, acc.z); acc.w = fmaf(b.w, w1, acc.w);
        }
        for (; t < nt; ++t) {
            int e = 4 * t + g;
            int s = __shfl(sIdx, e, 64);
            float ns = SCALED ? 1.0f : __shfl(nv, e, 64);
            float4 a = featv[(size_t)s * 16 + r];
            float w0 = (e < m) ? ns : 0.0f;
            acc.x = fmaf(a.x, w0, acc.x); acc.y = fmaf(a.y, w0, acc.y);
            acc.z = fmaf(a.z, w0, acc.z); acc.w = fmaf(a.w, w0, acc.w);
        }
    }

    acc.x += __shfl_xor(acc.x, 16, 64); acc.y += __shfl_xor(acc.y, 16, 64);
    acc.z += __shfl_xor(acc.z, 16, 64); acc.w += __shfl_xor(acc.w, 16, 64);
    acc.x += __shfl_xor(acc.x, 32, 64); acc.y += __shfl_xor(acc.y, 32, 64);
    acc.z += __shfl_xor(acc.z, 32, 64); acc.w += __shfl_xor(acc.w, 32, 64);

    float alpha = alpha_p[0];
    float sn = normv[n] * (1.0f - alpha);
    float4 f0 = feat04[(size_t)n * 16 + r];
    float4 fs;
    fs.x = fmaf(acc.x, sn, f0.x * alpha);
    fs.y = fmaf(acc.y, sn, f0.y * alpha);
    fs.z = fmaf(acc.z, sn, f0.z * alpha);
    fs.w = fmaf(acc.w, sn, f0.w * alpha);

    float4 res = make_float4(0.f, 0.f, 0.f, 0.f);
    #pragma unroll
    for (int kk = 0; kk < 16; ++kk) {
        int srcLane = 4 * g + (kk >> 2);
        float fscomp = ((kk & 3) == 0) ? fs.x : ((kk & 3) == 1) ? fs.y
                     : ((kk & 3) == 2) ? fs.z : fs.w;
        float fsk = __shfl(fscomp, srcLane, 64);
        float4 wv = sW[(16 * g + kk) * 16 + (r ^ g)];
        res.x = fmaf(fsk, wv.x, res.x);
        res.y = fmaf(fsk, wv.y, res.y);
        res.z = fmaf(fsk, wv.z, res.z);
        res.w = fmaf(fsk, wv.w, res.w);
    }
    res.x += __shfl_xor(res.x, 16, 64); res.y += __shfl_xor(res.y, 16, 64);
    res.z += __shfl_xor(res.z, 16, 64); res.w += __shfl_xor(res.w, 16, 64);
    res.x += __shfl_xor(res.x, 32, 64); res.y += __shfl_xor(res.y, 32, 64);
    res.z += __shfl_xor(res.z, 32, 64); res.w += __shfl_xor(res.w, 32, 64);

    if (g == 0) out4[(size_t)n * 16 + r] = res;
}

// ---------------- last-resort fallback (atomic scatter path) ----------------

__global__ void deg_kernel(const int* __restrict__ dst, float* __restrict__ degs, int nE) {
    int i = blockIdx.x * blockDim.x + threadIdx.x;
    if (i < nE) atomAddF(&degs[dst[i]], 1.0f);
}

__global__ void norm_kernel(float* degs, int nN) {
    int i = blockIdx.x * blockDim.x + threadIdx.x;
    if (i < nN) degs[i] = rsqrtf(fmaxf(degs[i], 1.0f));
}

__global__ void wp_kernel(const float* __restrict__ W, const float* __restrict__ lamda_p,
                          const int* __restrict__ layer_p, float* __restrict__ Wp) {
    int i = blockIdx.x * blockDim.x + threadIdx.x;
    if (i < DDIM * DDIM) {
        float lam = lamda_p[0];
        int lb = layer_p[0];
        float layerf = (lb > 0 && lb < (1 << 23)) ? (float)lb : __int_as_float(lb);
        float beta = logf(lam / layerf + 1.0f);
        int k = i >> 6, d = i & 63;
        float w = beta * W[i];
        if (k == d) w += (1.0f - beta);
        Wp[i] = w;
    }
}

__global__ void scatter_kernel(const float* __restrict__ feat, const float* __restrict__ norm,
                               const int* __restrict__ src, const int* __restrict__ dst,
                               float* __restrict__ accum, int nE) {
    long long gid = (long long)blockIdx.x * blockDim.x + threadIdx.x;
    int e = (int)(gid >> 6);
    int d = (int)(gid & 63);
    if (e < nE) {
        int s = src[e];
        int t = dst[e];
        float v = feat[(size_t)s * DDIM + d] * norm[s];
        atomAddF(&accum[(size_t)t * DDIM + d], v);
    }
}

__global__ void final_kernel(float* __restrict__ out, const float* __restrict__ feat0,
                             const float* __restrict__ norm, const float* __restrict__ Wp,
                             const float* __restrict__ alpha_p, int nN) {
    __shared__ float sW[DDIM * DDIM];
    for (int i = threadIdx.x; i < DDIM * DDIM; i += blockDim.x) sW[i] = Wp[i];
    __syncthreads();
    float alpha = alpha_p[0];
    int lane = threadIdx.x & 63;
    int w = threadIdx.x >> 6;
    int wavesPerBlock = blockDim.x >> 6;
    int nGroups = (nN + wavesPerBlock - 1) / wavesPerBlock;
    for (int gi = blockIdx.x; gi < nGroups; gi += gridDim.x) {
        int n = gi * wavesPerBlock + w;
        bool valid = n < nN;
        float fs = 0.0f;
        if (valid) {
            fs = out[(size_t)n * DDIM + lane] * norm[n] * (1.0f - alpha)
               + feat0[(size_t)n * DDIM + lane] * alpha;
        }
        float acc = 0.0f;
        #pragma unroll
        for (int k = 0; k < DDIM; ++k) {
            float fsk = __shfl(fs, k, 64);
            acc = fmaf(fsk, sW[k * DDIM + lane], acc);
        }
        if (valid) out[(size_t)n * DDIM + lane] = acc;
    }
}

// ---------------- launch ----------------

static inline size_t align256(size_t x) { return (x + 255) & ~(size_t)255; }

extern "C" void kernel_launch(void* const* d_in, const int* in_sizes, int n_in,
                              void* d_out, int out_size, void* d_ws, size_t ws_size,
                              hipStream_t stream) {
    const float* feat  = (const float*)d_in[0];
    const float* feat0 = (const float*)d_in[1];
    const float* W     = (const float*)d_in[2];
    const int*   src   = (const int*)d_in[3];
    const int*   dst   = (const int*)d_in[4];
    const float* alpha = (const float*)d_in[5];
    const float* lamda = (const float*)d_in[6];
    const int*   layer = (const int*)d_in[7];
    float* out = (float*)d_out;

    int nN = in_sizes[0] / DDIM;
    int nE = in_sizes[3];
    int NS = (nN + 255) >> 8;
    int nb = (nN + SCAN_CHUNK - 1) / SCAN_CHUNK;

    // ---- new-path workspace layout ----
    size_t off = 0;
    size_t o_degI  = off; off += align256((size_t)nN * 4);
    size_t o_norm  = off; off += align256((size_t)nN * 4);
    size_t o_rowe  = off; off += align256((size_t)nN * 4);
    size_t o_sbase = off; off += align256((size_t)(NS + 1) * 4);
    size_t o_scnt  = off; off += align256((size_t)NS * 4);
    size_t o_wp    = off; off += align256((size_t)DDIM * DDIM * 4);
    size_t o_eidx  = off; off += align256((size_t)nE * 4);
    size_t base_sz = off;
    size_t o_featS = off; off += align256((size_t)nN * DDIM * 4);
    size_t need_t1 = off;                                 // staging aliased into featS
    size_t o_stag2 = base_sz;
    size_t need_t2 = base_sz + align256((size_t)nE * 4);  // staging separate, no featS

    bool newok = (NS >= 1 && NS <= MAXNS && nN <= (1 << 24));
    bool t1ok  = newok && ws_size >= need_t1 && ((size_t)nE * 4 <= (size_t)nN * DDIM * 4);
    bool t2ok  = newok && ws_size >= need_t2;

    if (t1ok || t2ok) {
        int*      degI  = (int*)  ((char*)d_ws + o_degI);
        float*    normv = (float*)((char*)d_ws + o_norm);
        int*      rowe  = (int*)  ((char*)d_ws + o_rowe);
        int*      sbase = (int*)  ((char*)d_ws + o_sbase);
        int*      scnt  = (int*)  ((char*)d_ws + o_scnt);
        float*    Wp    = (float*)((char*)d_ws + o_wp);
        int*      eidx  = (int*)  ((char*)d_ws + o_eidx);
        unsigned* stag  = (unsigned*)((char*)d_ws + (t1ok ? o_featS : o_stag2));
        float*    featS = (float*)((char*)d_ws + o_featS);

        hipMemsetAsync(scnt, 0, (size_t)NS * 4, stream);
        int pblocks = (nE + PART_EPB - 1) / PART_EPB;
        if (pblocks < 1) pblocks = 1;
        slice_count_kernel<<<pblocks, PART_TPB, 0, stream>>>(dst, scnt, nE, NS);
        slice_scan_wp_kernel<<<1, 512, 0, stream>>>(scnt, sbase, NS, nE, W, lamda, layer, Wp);
        partition_kernel<<<pblocks, PART_TPB, 0, stream>>>(src, dst, scnt, stag, nE, NS);
        bin_fill_kernel<<<NS, 256, 0, stream>>>(stag, sbase, degI, normv, rowe, eidx, nN);

        int gblocks = (nN + 3) / 4;
        if (t1ok) {
            // staging region dead after bin_fill; featS overwrites it (stream-ordered)
            scale_kernel<<<(nN + 15) / 16, 256, 0, stream>>>(
                (const float4*)feat, normv, (float4*)featS, nN);
            gather_kernel<true><<<gblocks, 256, 0, stream>>>(
                (const float4*)featS, (const float4*)feat0, normv, degI, rowe, eidx,
                Wp, alpha, (float4*)out, nN);
        } else {
            gather_kernel<false><<<gblocks, 256, 0, stream>>>(
                (const float4*)feat, (const float4*)feat0, normv, degI, rowe, eidx,
                Wp, alpha, (float4*)out, nN);
        }
        return;
    }

    // ---- old CSR path (fallback) ----
    off = 0;
    size_t f_degI = off;      off += align256((size_t)nN * 4);
    size_t f_norm = off;      off += align256((size_t)nN * 4);
    size_t f_rows = off;      off += align256((size_t)nN * 4);
    size_t f_bsum = off;      off += align256((size_t)nb * 4);
    size_t f_wp   = off;      off += align256((size_t)DDIM * DDIM * 4);
    size_t f_eidx = off;      off += align256((size_t)nE * 4);
    size_t need_csr = off;
    size_t f_featS = off;     off += align256((size_t)nN * DDIM * 4);
    size_t need_full = off;

    if (ws_size >= need_csr && nb <= SCAN_BLOCK) {
        int*   degI  = (int*)  ((char*)d_ws + f_degI);
        float* normv = (float*)((char*)d_ws + f_norm);
        int*   rows  = (int*)  ((char*)d_ws + f_rows);
        int*   bsum  = (int*)  ((char*)d_ws + f_bsum);
        float* Wp    = (float*)((char*)d_ws + f_wp);
        int*   eidx  = (int*)  ((char*)d_ws + f_eidx);
        bool scaled = (ws_size >= need_full);
        float* featS = (float*)((char*)d_ws + f_featS);

        hipMemsetAsync(degI, 0, (size_t)nN * 4, stream);
        int e4blocks = ((nE + 3) / 4 + 255) / 256;
        deg_int_kernel<<<e4blocks, 256, 0, stream>>>(dst, degI, nE);
        scan1_kernel<<<nb, SCAN_BLOCK, 0, stream>>>(degI, rows, normv, bsum, nN);
        scan2_wp_kernel<<<1, SCAN_BLOCK, 0, stream>>>(bsum, nb, W, lamda, layer, Wp);
        if (scaled) {
            scan3_scale_kernel<<<(nN + 15) / 16, 256, 0, stream>>>(
                rows, bsum, (const float4*)feat, normv, (float4*)featS, nN);
        } else {
            scan3_kernel<<<(nN + 255) / 256, 256, 0, stream>>>(rows, bsum, nN);
        }
        fill_kernel<<<e4blocks, 256, 0, stream>>>(src, dst, rows, eidx, nE);

        int gblocks = (nN + 3) / 4;
        if (scaled) {
            gather_kernel<true><<<gblocks, 256, 0, stream>>>(
                (const float4*)featS, (const float4*)feat0, normv, degI, rows, eidx,
                Wp, alpha, (float4*)out, nN);
        } else {
            gather_kernel<false><<<gblocks, 256, 0, stream>>>(
                (const float4*)feat, (const float4*)feat0, normv, degI, rows, eidx,
                Wp, alpha, (float4*)out, nN);
        }
    } else {
        float* degs = (float*)d_ws;
        size_t degs_bytes_al = align256((size_t)nN * 4);
        float* Wp = (float*)((char*)d_ws + degs_bytes_al);

        hipMemsetAsync(out, 0, (size_t)out_size * sizeof(float), stream);
        hipMemsetAsync(degs, 0, (size_t)nN * sizeof(float), stream);

        deg_kernel<<<(nE + 255) / 256, 256, 0, stream>>>(dst, degs, nE);
        norm_kernel<<<(nN + 255) / 256, 256, 0, stream>>>(degs, nN);
        wp_kernel<<<(DDIM * DDIM + 255) / 256, 256, 0, stream>>>(W, lamda, layer, Wp);

        long long tot = (long long)nE * DDIM;
        int sblocks = (int)((tot + 255) / 256);
        scatter_kernel<<<sblocks, 256, 0, stream>>>(feat, degs, src, dst, out, nE);
        final_kernel<<<2048, 256, 0, stream>>>(out, feat0, degs, Wp, alpha, nN);
    }
}

// Round 2
// 132.907 us; speedup vs baseline: 1.7861x; 1.0166x over previous
//
#include <hip/hip_runtime.h>
#include <hip/hip_fp16.h>

#define DDIM 64
#define MAXNS 2048          // max slices (nodes/256) handled by the new path
#define PART_TPB 256
#define PART_EPT 16
#define PART_EPB (PART_TPB * PART_EPT)   // 4096 edges per block

__device__ __forceinline__ float atomAddF(float* p, float v) {
    return unsafeAtomicAdd(p, v);   // HW global_atomic_add_f32 on gfx950
}

// ================= CSR BUILD: two-level counting sort by dst>>8 =================

// Pass 1: per-slice edge counts (LDS-aggregated histogram)
__global__ void slice_count_kernel(const int* __restrict__ dst, int* __restrict__ sliceCnt,
                                   int nE, int NS) {
    __shared__ int lh[MAXNS];
    int t = threadIdx.x;
    int blockBase = blockIdx.x * PART_EPB;
    for (int i = t; i < NS; i += PART_TPB) lh[i] = 0;
    __syncthreads();
    #pragma unroll
    for (int c = 0; c < 4; ++c) {
        int e0 = blockBase + (c * PART_TPB + t) * 4;
        if (e0 + 3 < nE) {
            int4 b = *(const int4*)(dst + e0);
            atomicAdd(&lh[b.x >> 8], 1); atomicAdd(&lh[b.y >> 8], 1);
            atomicAdd(&lh[b.z >> 8], 1); atomicAdd(&lh[b.w >> 8], 1);
        } else {
            for (int j = 0; j < 4; ++j) {
                int e = e0 + j;
                if (e < nE) atomicAdd(&lh[dst[e] >> 8], 1);
            }
        }
    }
    __syncthreads();
    for (int i = t; i < NS; i += PART_TPB)
        if (lh[i]) atomicAdd(&sliceCnt[i], lh[i]);
}

// Pass 2 (1 block): exclusive scan of slice counts -> sliceBase[] (persistent)
// and scnt[] reused as running cursors for partition. Fused Wp build.
__global__ void slice_scan_wp_kernel(int* __restrict__ scnt, int* __restrict__ sbase,
                                     int NS, int nE,
                                     const float* __restrict__ W, const float* __restrict__ lamda_p,
                                     const int* __restrict__ layer_p, float* __restrict__ Wp) {
    __shared__ int sdata[512];
    int t = threadIdx.x;
    int base = t * 4;
    int v[4];
    #pragma unroll
    for (int j = 0; j < 4; ++j) {
        int idx = base + j;
        v[j] = (idx < NS) ? scnt[idx] : 0;
    }
    int local = v[0] + v[1] + v[2] + v[3];
    sdata[t] = local;
    __syncthreads();
    for (int off = 1; off < 512; off <<= 1) {
        int y = (t >= off) ? sdata[t - off] : 0;
        __syncthreads();
        sdata[t] += y;
        __syncthreads();
    }
    int run = sdata[t] - local;
    #pragma unroll
    for (int j = 0; j < 4; ++j) {
        int idx = base + j;
        if (idx < NS) { sbase[idx] = run; scnt[idx] = run; }
        run += v[j];
    }
    if (t == 0) sbase[NS] = nE;

    float lam = lamda_p[0];
    int lb = layer_p[0];
    float layerf = (lb > 0 && lb < (1 << 23)) ? (float)lb : __int_as_float(lb);
    float beta = logf(lam / layerf + 1.0f);
    for (int i = t; i < DDIM * DDIM; i += 512) {
        int k = i >> 6, d = i & 63;
        float w = beta * W[i];
        if (k == d) w += (1.0f - beta);
        Wp[i] = w;
    }
}

// Pass 3: scatter packed (src<<8 | dstLow) into per-slice staging regions.
__global__ void partition_kernel(const int* __restrict__ src, const int* __restrict__ dst,
                                 int* __restrict__ cursor, unsigned* __restrict__ staging,
                                 int nE, int NS) {
    __shared__ int lh[MAXNS];
    __shared__ int lbase[MAXNS];
    int t = threadIdx.x;
    int blockBase = blockIdx.x * PART_EPB;
    for (int i = t; i < NS; i += PART_TPB) lh[i] = 0;
    __syncthreads();

    int se[PART_EPT]; int de[PART_EPT];
    #pragma unroll
    for (int c = 0; c < 4; ++c) {
        int e0 = blockBase + (c * PART_TPB + t) * 4;
        if (e0 + 3 < nE) {
            int4 a = *(const int4*)(src + e0);
            int4 b = *(const int4*)(dst + e0);
            se[4*c+0] = a.x; se[4*c+1] = a.y; se[4*c+2] = a.z; se[4*c+3] = a.w;
            de[4*c+0] = b.x; de[4*c+1] = b.y; de[4*c+2] = b.z; de[4*c+3] = b.w;
        } else {
            #pragma unroll
            for (int j = 0; j < 4; ++j) {
                int e = e0 + j;
                se[4*c+j] = (e < nE) ? src[e] : 0;
                de[4*c+j] = (e < nE) ? dst[e] : -1;
            }
        }
    }
    #pragma unroll
    for (int k = 0; k < PART_EPT; ++k)
        if (de[k] >= 0) atomicAdd(&lh[de[k] >> 8], 1);
    __syncthreads();
    for (int i = t; i < NS; i += PART_TPB) {
        int c = lh[i];
        if (c) lbase[i] = atomicAdd(&cursor[i], c);
        lh[i] = 0;
    }
    __syncthreads();
    #pragma unroll
    for (int k = 0; k < PART_EPT; ++k) {
        int d = de[k];
        if (d >= 0) {
            int sl = d >> 8;
            int off = atomicAdd(&lh[sl], 1);
            staging[lbase[sl] + off] = ((unsigned)se[k] << 8) | (unsigned)(d & 255);
        }
    }
}

// Pass 4: one block per slice. Histogram 256 local nodes (== degI), LDS scan
// (== row_end), write normv, then scatter eidx inside an L2-resident window.
__global__ void bin_fill_kernel(const unsigned* __restrict__ staging, const int* __restrict__ sbase,
                                int* __restrict__ degI, float* __restrict__ normv,
                                int* __restrict__ row_end, int* __restrict__ eidx, int nN) {
    __shared__ int cnt[256];
    __shared__ int pos[256];
    int s = blockIdx.x;
    int t = threadIdx.x;
    int b0 = sbase[s], b1 = sbase[s + 1];
    cnt[t] = 0;
    __syncthreads();
    for (int j = b0 + t; j < b1; j += 256) {
        unsigned p = staging[j];
        atomicAdd(&cnt[p & 255], 1);
    }
    __syncthreads();
    int c = cnt[t];
    pos[t] = c;
    __syncthreads();
    for (int off = 1; off < 256; off <<= 1) {
        int y = (t >= off) ? pos[t - off] : 0;
        __syncthreads();
        pos[t] += y;
        __syncthreads();
    }
    int inc = pos[t];
    int exc = inc - c;
    int node = (s << 8) + t;
    if (node < nN) {
        degI[node] = c;
        normv[node] = rsqrtf(fmaxf((float)c, 1.0f));
        row_end[node] = b0 + inc;
    }
    pos[t] = b0 + exc;
    __syncthreads();
    for (int j = b0 + t; j < b1; j += 256) {
        unsigned p = staging[j];
        int q = atomicAdd(&pos[p & 255], 1);
        eidx[q] = (int)(p >> 8);
    }
}

// featS(fp16) = feat * norm[node]; lane holds 4 dims -> 8B (uint2) per lane
__global__ void scale_kernel(const float4* __restrict__ feat4, const float* __restrict__ normv,
                             uint2* __restrict__ featS2, int nN) {
    int b = blockIdx.x, t = threadIdx.x;
    int node = b * 16 + (t >> 4);
    int r = t & 15;
    if (node < nN) {
        float nv = normv[node];
        float4 v = feat4[(size_t)node * 16 + r];
        __half2 h0 = __floats2half2_rn(v.x * nv, v.y * nv);
        __half2 h1 = __floats2half2_rn(v.z * nv, v.w * nv);
        uint2 u;
        u.x = *(unsigned*)&h0;
        u.y = *(unsigned*)&h1;
        featS2[(size_t)node * 16 + r] = u;
    }
}

// ================= OLD CSR BUILD (fallback tier) =================

__global__ void deg_int_kernel(const int* __restrict__ dst, int* __restrict__ degI, int nE) {
    int i = blockIdx.x * blockDim.x + threadIdx.x;
    int base = i * 4;
    if (base + 3 < nE) {
        int4 d = *(const int4*)(dst + base);
        atomicAdd(&degI[d.x], 1); atomicAdd(&degI[d.y], 1);
        atomicAdd(&degI[d.z], 1); atomicAdd(&degI[d.w], 1);
    } else {
        for (int j = base; j < nE; ++j) atomicAdd(&degI[dst[j]], 1);
    }
}

#define SCAN_BLOCK 256
#define SCAN_CHUNK 1024

__global__ void scan1_kernel(const int* __restrict__ degI, int* __restrict__ row_start,
                             float* __restrict__ normv, int* __restrict__ blockSums, int nN) {
    __shared__ int sdata[SCAN_BLOCK];
    int t = threadIdx.x;
    int base = blockIdx.x * SCAN_CHUNK + t * 4;
    int v[4];
    #pragma unroll
    for (int j = 0; j < 4; ++j) {
        int idx = base + j;
        v[j] = (idx < nN) ? degI[idx] : 0;
    }
    int local = v[0] + v[1] + v[2] + v[3];
    sdata[t] = local;
    __syncthreads();
    for (int off = 1; off < SCAN_BLOCK; off <<= 1) {
        int y = (t >= off) ? sdata[t - off] : 0;
        __syncthreads();
        sdata[t] += y;
        __syncthreads();
    }
    int inc = sdata[t];
    int exc = inc - local;
    if (t == SCAN_BLOCK - 1) blockSums[blockIdx.x] = inc;
    int run = exc;
    #pragma unroll
    for (int j = 0; j < 4; ++j) {
        int idx = base + j;
        if (idx < nN) {
            row_start[idx] = run;
            normv[idx] = rsqrtf(fmaxf((float)v[j], 1.0f));
        }
        run += v[j];
    }
}

__global__ void scan2_wp_kernel(int* __restrict__ blockSums, int nb,
                                const float* __restrict__ W, const float* __restrict__ lamda_p,
                                const int* __restrict__ layer_p, float* __restrict__ Wp) {
    __shared__ int sdata[SCAN_BLOCK];
    int t = threadIdx.x;
    int v = (t < nb) ? blockSums[t] : 0;
    sdata[t] = v;
    __syncthreads();
    for (int off = 1; off < SCAN_BLOCK; off <<= 1) {
        int y = (t >= off) ? sdata[t - off] : 0;
        __syncthreads();
        sdata[t] += y;
        __syncthreads();
    }
    if (t < nb) blockSums[t] = sdata[t] - v;

    float lam = lamda_p[0];
    int lb = layer_p[0];
    float layerf = (lb > 0 && lb < (1 << 23)) ? (float)lb : __int_as_float(lb);
    float beta = logf(lam / layerf + 1.0f);
    for (int i = t; i < DDIM * DDIM; i += SCAN_BLOCK) {
        int k = i >> 6, d = i & 63;
        float w = beta * W[i];
        if (k == d) w += (1.0f - beta);
        Wp[i] = w;
    }
}

// add block offsets to row_start AND produce featS(fp16)
__global__ void scan3_scale_kernel(int* __restrict__ row_start, const int* __restrict__ blockSums,
                                   const float4* __restrict__ feat4, const float* __restrict__ normv,
                                   uint2* __restrict__ featS2, int nN) {
    int b = blockIdx.x, t = threadIdx.x;
    int node = b * 16 + (t >> 4);
    int r = t & 15;
    if (node < nN) {
        float nv = normv[node];
        float4 v = feat4[(size_t)node * 16 + r];
        __half2 h0 = __floats2half2_rn(v.x * nv, v.y * nv);
        __half2 h1 = __floats2half2_rn(v.z * nv, v.w * nv);
        uint2 u;
        u.x = *(unsigned*)&h0;
        u.y = *(unsigned*)&h1;
        featS2[(size_t)node * 16 + r] = u;
    }
    if (t < 16) {
        int n2 = b * 16 + t;
        if (n2 < nN) row_start[n2] += blockSums[n2 >> 10];
    }
}

__global__ void scan3_kernel(int* __restrict__ row_start, const int* __restrict__ blockSums, int nN) {
    int i = blockIdx.x * blockDim.x + threadIdx.x;
    if (i < nN) row_start[i] += blockSums[i >> 10];
}

__global__ void fill_kernel(const int* __restrict__ src, const int* __restrict__ dst,
                            int* __restrict__ row_start, int* __restrict__ eidx, int nE) {
    int i = blockIdx.x * blockDim.x + threadIdx.x;
    int base = i * 4;
    if (base + 3 < nE) {
        int4 s = *(const int4*)(src + base);
        int4 d = *(const int4*)(dst + base);
        eidx[atomicAdd(&row_start[d.x], 1)] = s.x;
        eidx[atomicAdd(&row_start[d.y], 1)] = s.y;
        eidx[atomicAdd(&row_start[d.z], 1)] = s.z;
        eidx[atomicAdd(&row_start[d.w], 1)] = s.w;
    } else {
        for (int j = base; j < nE; ++j) {
            int tt = dst[j];
            int p = atomicAdd(&row_start[tt], 1);
            eidx[p] = src[j];
        }
    }
}

// ---------------- fused gather + epilogue (wave per node, 4x16 lane layout) ----------------
// HALF=true: featv is fp16 featS (pre-scaled), 8B/lane rows.
// HALF=false: featv is fp32 feat (unscaled), 16B/lane rows, per-src norm via shfl.
// Grid-stride over nodes so sW staging amortizes across many nodes per block.
template<bool HALF>
__global__ void gather_kernel(const void* __restrict__ featv_, const float4* __restrict__ feat04,
                              const float* __restrict__ normv, const int* __restrict__ degI,
                              const int* __restrict__ row_end, const int* __restrict__ eidx,
                              const float* __restrict__ Wp, const float* __restrict__ alpha_p,
                              float4* __restrict__ out4, int nN) {
    __shared__ float4 sW[DDIM * 16];   // 16 KiB, XOR-swizzled
    const float4* Wp4 = (const float4*)Wp;
    for (int i = threadIdx.x; i < DDIM * 16; i += blockDim.x) {
        sW[(i & ~15) | ((i & 15) ^ ((i >> 8) & 3))] = Wp4[i];
    }
    __syncthreads();

    const float4* featF = (const float4*)featv_;
    const uint2*  featH = (const uint2*)featv_;

    int lane = threadIdx.x & 63;
    int w = threadIdx.x >> 6;
    int g = lane >> 4;
    int r = lane & 15;
    float alpha = alpha_p[0];

    for (int n = blockIdx.x * 4 + w; n < nN; n += gridDim.x * 4) {
        int end = row_end[n];
        int deg = degI[n];
        int start = end - deg;

        float4 acc = make_float4(0.f, 0.f, 0.f, 0.f);

        for (int j0 = start; j0 < end; j0 += 64) {
            int m = end - j0; if (m > 64) m = 64;
            int sIdx = 0;
            float nv = 1.0f;
            if (lane < m) {
                sIdx = eidx[j0 + lane];
                if (!HALF) nv = normv[sIdx];
            }
            int nt = (m + 3) >> 2;
            int t = 0;
            for (; t + 2 <= nt; t += 2) {
                int e0 = 4 * t + g, e1 = e0 + 4;
                int s0 = __shfl(sIdx, e0, 64);
                int s1 = __shfl(sIdx, e1, 64);
                float w0 = (e0 < m) ? 1.0f : 0.0f;
                float w1 = (e1 < m) ? 1.0f : 0.0f;
                if (HALF) {
                    uint2 ua = featH[(size_t)s0 * 16 + r];
                    uint2 ub = featH[(size_t)s1 * 16 + r];
                    float2 a0 = __half22float2(*(const __half2*)&ua.x);
                    float2 a1 = __half22float2(*(const __half2*)&ua.y);
                    float2 b0 = __half22float2(*(const __half2*)&ub.x);
                    float2 b1 = __half22float2(*(const __half2*)&ub.y);
                    acc.x = fmaf(a0.x, w0, acc.x); acc.y = fmaf(a0.y, w0, acc.y);
                    acc.z = fmaf(a1.x, w0, acc.z); acc.w = fmaf(a1.y, w0, acc.w);
                    acc.x = fmaf(b0.x, w1, acc.x); acc.y = fmaf(b0.y, w1, acc.y);
                    acc.z = fmaf(b1.x, w1, acc.z); acc.w = fmaf(b1.y, w1, acc.w);
                } else {
                    float ns0 = __shfl(nv, e0, 64);
                    float ns1 = __shfl(nv, e1, 64);
                    w0 *= ns0; w1 *= ns1;
                    float4 a = featF[(size_t)s0 * 16 + r];
                    float4 b = featF[(size_t)s1 * 16 + r];
                    acc.x = fmaf(a.x, w0, acc.x); acc.y = fmaf(a.y, w0, acc.y);
                    acc.z = fmaf(a.z, w0, acc.z); acc.w = fmaf(a.w, w0, acc.w);
                    acc.x = fmaf(b.x, w1, acc.x); acc.y = fmaf(b.y, w1, acc.y);
                    acc.z = fmaf(b.z, w1, acc.z); acc.w = fmaf(b.w, w1, acc.w);
                }
            }
            for (; t < nt; ++t) {
                int e = 4 * t + g;
                int s = __shfl(sIdx, e, 64);
                float w0 = (e < m) ? 1.0f : 0.0f;
                if (HALF) {
                    uint2 ua = featH[(size_t)s * 16 + r];
                    float2 a0 = __half22float2(*(const __half2*)&ua.x);
                    float2 a1 = __half22float2(*(const __half2*)&ua.y);
                    acc.x = fmaf(a0.x, w0, acc.x); acc.y = fmaf(a0.y, w0, acc.y);
                    acc.z = fmaf(a1.x, w0, acc.z); acc.w = fmaf(a1.y, w0, acc.w);
                } else {
                    float ns = __shfl(nv, e, 64);
                    w0 *= ns;
                    float4 a = featF[(size_t)s * 16 + r];
                    acc.x = fmaf(a.x, w0, acc.x); acc.y = fmaf(a.y, w0, acc.y);
                    acc.z = fmaf(a.z, w0, acc.z); acc.w = fmaf(a.w, w0, acc.w);
                }
            }
        }

        acc.x += __shfl_xor(acc.x, 16, 64); acc.y += __shfl_xor(acc.y, 16, 64);
        acc.z += __shfl_xor(acc.z, 16, 64); acc.w += __shfl_xor(acc.w, 16, 64);
        acc.x += __shfl_xor(acc.x, 32, 64); acc.y += __shfl_xor(acc.y, 32, 64);
        acc.z += __shfl_xor(acc.z, 32, 64); acc.w += __shfl_xor(acc.w, 32, 64);

        float sn = normv[n] * (1.0f - alpha);
        float4 f0 = feat04[(size_t)n * 16 + r];
        float4 fs;
        fs.x = fmaf(acc.x, sn, f0.x * alpha);
        fs.y = fmaf(acc.y, sn, f0.y * alpha);
        fs.z = fmaf(acc.z, sn, f0.z * alpha);
        fs.w = fmaf(acc.w, sn, f0.w * alpha);

        float4 res = make_float4(0.f, 0.f, 0.f, 0.f);
        #pragma unroll
        for (int kk = 0; kk < 16; ++kk) {
            int srcLane = 4 * g + (kk >> 2);
            float fscomp = ((kk & 3) == 0) ? fs.x : ((kk & 3) == 1) ? fs.y
                         : ((kk & 3) == 2) ? fs.z : fs.w;
            float fsk = __shfl(fscomp, srcLane, 64);
            float4 wv = sW[(16 * g + kk) * 16 + (r ^ g)];
            res.x = fmaf(fsk, wv.x, res.x);
            res.y = fmaf(fsk, wv.y, res.y);
            res.z = fmaf(fsk, wv.z, res.z);
            res.w = fmaf(fsk, wv.w, res.w);
        }
        res.x += __shfl_xor(res.x, 16, 64); res.y += __shfl_xor(res.y, 16, 64);
        res.z += __shfl_xor(res.z, 16, 64); res.w += __shfl_xor(res.w, 16, 64);
        res.x += __shfl_xor(res.x, 32, 64); res.y += __shfl_xor(res.y, 32, 64);
        res.z += __shfl_xor(res.z, 32, 64); res.w += __shfl_xor(res.w, 32, 64);

        if (g == 0) out4[(size_t)n * 16 + r] = res;
    }
}

// ---------------- last-resort fallback (atomic scatter path) ----------------

__global__ void deg_kernel(const int* __restrict__ dst, float* __restrict__ degs, int nE) {
    int i = blockIdx.x * blockDim.x + threadIdx.x;
    if (i < nE) atomAddF(&degs[dst[i]], 1.0f);
}

__global__ void norm_kernel(float* degs, int nN) {
    int i = blockIdx.x * blockDim.x + threadIdx.x;
    if (i < nN) degs[i] = rsqrtf(fmaxf(degs[i], 1.0f));
}

__global__ void wp_kernel(const float* __restrict__ W, const float* __restrict__ lamda_p,
                          const int* __restrict__ layer_p, float* __restrict__ Wp) {
    int i = blockIdx.x * blockDim.x + threadIdx.x;
    if (i < DDIM * DDIM) {
        float lam = lamda_p[0];
        int lb = layer_p[0];
        float layerf = (lb > 0 && lb < (1 << 23)) ? (float)lb : __int_as_float(lb);
        float beta = logf(lam / layerf + 1.0f);
        int k = i >> 6, d = i & 63;
        float w = beta * W[i];
        if (k == d) w += (1.0f - beta);
        Wp[i] = w;
    }
}

__global__ void scatter_kernel(const float* __restrict__ feat, const float* __restrict__ norm,
                               const int* __restrict__ src, const int* __restrict__ dst,
                               float* __restrict__ accum, int nE) {
    long long gid = (long long)blockIdx.x * blockDim.x + threadIdx.x;
    int e = (int)(gid >> 6);
    int d = (int)(gid & 63);
    if (e < nE) {
        int s = src[e];
        int t = dst[e];
        float v = feat[(size_t)s * DDIM + d] * norm[s];
        atomAddF(&accum[(size_t)t * DDIM + d], v);
    }
}

__global__ void final_kernel(float* __restrict__ out, const float* __restrict__ feat0,
                             const float* __restrict__ norm, const float* __restrict__ Wp,
                             const float* __restrict__ alpha_p, int nN) {
    __shared__ float sW[DDIM * DDIM];
    for (int i = threadIdx.x; i < DDIM * DDIM; i += blockDim.x) sW[i] = Wp[i];
    __syncthreads();
    float alpha = alpha_p[0];
    int lane = threadIdx.x & 63;
    int w = threadIdx.x >> 6;
    int wavesPerBlock = blockDim.x >> 6;
    int nGroups = (nN + wavesPerBlock - 1) / wavesPerBlock;
    for (int gi = blockIdx.x; gi < nGroups; gi += gridDim.x) {
        int n = gi * wavesPerBlock + w;
        bool valid = n < nN;
        float fs = 0.0f;
        if (valid) {
            fs = out[(size_t)n * DDIM + lane] * norm[n] * (1.0f - alpha)
               + feat0[(size_t)n * DDIM + lane] * alpha;
        }
        float acc = 0.0f;
        #pragma unroll
        for (int k = 0; k < DDIM; ++k) {
            float fsk = __shfl(fs, k, 64);
            acc = fmaf(fsk, sW[k * DDIM + lane], acc);
        }
        if (valid) out[(size_t)n * DDIM + lane] = acc;
    }
}

// ---------------- launch ----------------

static inline size_t align256(size_t x) { return (x + 255) & ~(size_t)255; }

extern "C" void kernel_launch(void* const* d_in, const int* in_sizes, int n_in,
                              void* d_out, int out_size, void* d_ws, size_t ws_size,
                              hipStream_t stream) {
    const float* feat  = (const float*)d_in[0];
    const float* feat0 = (const float*)d_in[1];
    const float* W     = (const float*)d_in[2];
    const int*   src   = (const int*)d_in[3];
    const int*   dst   = (const int*)d_in[4];
    const float* alpha = (const float*)d_in[5];
    const float* lamda = (const float*)d_in[6];
    const int*   layer = (const int*)d_in[7];
    float* out = (float*)d_out;

    int nN = in_sizes[0] / DDIM;
    int nE = in_sizes[3];
    int NS = (nN + 255) >> 8;
    int nb = (nN + SCAN_CHUNK - 1) / SCAN_CHUNK;

    // ---- new-path workspace layout ----
    size_t off = 0;
    size_t o_degI  = off; off += align256((size_t)nN * 4);
    size_t o_norm  = off; off += align256((size_t)nN * 4);
    size_t o_rowe  = off; off += align256((size_t)nN * 4);
    size_t o_sbase = off; off += align256((size_t)(NS + 1) * 4);
    size_t o_scnt  = off; off += align256((size_t)NS * 4);
    size_t o_wp    = off; off += align256((size_t)DDIM * DDIM * 4);
    size_t o_eidx  = off; off += align256((size_t)nE * 4);
    size_t base_sz = off;
    size_t o_featS = off; off += align256((size_t)nN * DDIM * 2);   // fp16 featS
    size_t need_t1 = off;                                 // staging aliased into featS
    size_t o_stag2 = base_sz;
    size_t need_t2 = base_sz + align256((size_t)nE * 4);  // staging separate, no featS

    bool newok = (NS >= 1 && NS <= MAXNS && nN <= (1 << 23));
    bool t1ok  = newok && ws_size >= need_t1 && ((size_t)nE * 4 <= (size_t)nN * DDIM * 2);
    bool t2ok  = newok && ws_size >= need_t2;

    if (t1ok || t2ok) {
        int*      degI  = (int*)  ((char*)d_ws + o_degI);
        float*    normv = (float*)((char*)d_ws + o_norm);
        int*      rowe  = (int*)  ((char*)d_ws + o_rowe);
        int*      sbase = (int*)  ((char*)d_ws + o_sbase);
        int*      scnt  = (int*)  ((char*)d_ws + o_scnt);
        float*    Wp    = (float*)((char*)d_ws + o_wp);
        int*      eidx  = (int*)  ((char*)d_ws + o_eidx);
        unsigned* stag  = (unsigned*)((char*)d_ws + (t1ok ? o_featS : o_stag2));
        float*    featS = (float*)((char*)d_ws + o_featS);

        hipMemsetAsync(scnt, 0, (size_t)NS * 4, stream);
        int pblocks = (nE + PART_EPB - 1) / PART_EPB;
        if (pblocks < 1) pblocks = 1;
        slice_count_kernel<<<pblocks, PART_TPB, 0, stream>>>(dst, scnt, nE, NS);
        slice_scan_wp_kernel<<<1, 512, 0, stream>>>(scnt, sbase, NS, nE, W, lamda, layer, Wp);
        partition_kernel<<<pblocks, PART_TPB, 0, stream>>>(src, dst, scnt, stag, nE, NS);
        bin_fill_kernel<<<NS, 256, 0, stream>>>(stag, sbase, degI, normv, rowe, eidx, nN);

        int gblocks = (nN + 3) / 4;
        if (gblocks > 4096) gblocks = 4096;
        if (t1ok) {
            // staging region dead after bin_fill; featS overwrites it (stream-ordered)
            scale_kernel<<<(nN + 15) / 16, 256, 0, stream>>>(
                (const float4*)feat, normv, (uint2*)featS, nN);
            gather_kernel<true><<<gblocks, 256, 0, stream>>>(
                (const void*)featS, (const float4*)feat0, normv, degI, rowe, eidx,
                Wp, alpha, (float4*)out, nN);
        } else {
            gather_kernel<false><<<gblocks, 256, 0, stream>>>(
                (const void*)feat, (const float4*)feat0, normv, degI, rowe, eidx,
                Wp, alpha, (float4*)out, nN);
        }
        return;
    }

    // ---- old CSR path (fallback) ----
    off = 0;
    size_t f_degI = off;      off += align256((size_t)nN * 4);
    size_t f_norm = off;      off += align256((size_t)nN * 4);
    size_t f_rows = off;      off += align256((size_t)nN * 4);
    size_t f_bsum = off;      off += align256((size_t)nb * 4);
    size_t f_wp   = off;      off += align256((size_t)DDIM * DDIM * 4);
    size_t f_eidx = off;      off += align256((size_t)nE * 4);
    size_t need_csr = off;
    size_t f_featS = off;     off += align256((size_t)nN * DDIM * 2);
    size_t need_full = off;

    if (ws_size >= need_csr && nb <= SCAN_BLOCK) {
        int*   degI  = (int*)  ((char*)d_ws + f_degI);
        float* normv = (float*)((char*)d_ws + f_norm);
        int*   rows  = (int*)  ((char*)d_ws + f_rows);
        int*   bsum  = (int*)  ((char*)d_ws + f_bsum);
        float* Wp    = (float*)((char*)d_ws + f_wp);
        int*   eidx  = (int*)  ((char*)d_ws + f_eidx);
        bool scaled = (ws_size >= need_full);
        float* featS = (float*)((char*)d_ws + f_featS);

        hipMemsetAsync(degI, 0, (size_t)nN * 4, stream);
        int e4blocks = ((nE + 3) / 4 + 255) / 256;
        deg_int_kernel<<<e4blocks, 256, 0, stream>>>(dst, degI, nE);
        scan1_kernel<<<nb, SCAN_BLOCK, 0, stream>>>(degI, rows, normv, bsum, nN);
        scan2_wp_kernel<<<1, SCAN_BLOCK, 0, stream>>>(bsum, nb, W, lamda, layer, Wp);
        if (scaled) {
            scan3_scale_kernel<<<(nN + 15) / 16, 256, 0, stream>>>(
                rows, bsum, (const float4*)feat, normv, (uint2*)featS, nN);
        } else {
            scan3_kernel<<<(nN + 255) / 256, 256, 0, stream>>>(rows, bsum, nN);
        }
        fill_kernel<<<e4blocks, 256, 0, stream>>>(src, dst, rows, eidx, nE);

        int gblocks = (nN + 3) / 4;
        if (gblocks > 4096) gblocks = 4096;
        if (scaled) {
            gather_kernel<true><<<gblocks, 256, 0, stream>>>(
                (const void*)featS, (const float4*)feat0, normv, degI, rows, eidx,
                Wp, alpha, (float4*)out, nN);
        } else {
            gather_kernel<false><<<gblocks, 256, 0, stream>>>(
                (const void*)feat, (const float4*)feat0, normv, degI, rows, eidx,
                Wp, alpha, (float4*)out, nN);
        }
    } else {
        float* degs = (float*)d_ws;
        size_t degs_bytes_al = align256((size_t)nN * 4);
        float* Wp = (float*)((char*)d_ws + degs_bytes_al);

        hipMemsetAsync(out, 0, (size_t)out_size * sizeof(float), stream);
        hipMemsetAsync(degs, 0, (size_t)nN * sizeof(float), stream);

        deg_kernel<<<(nE + 255) / 256, 256, 0, stream>>>(dst, degs, nE);
        norm_kernel<<<(nN + 255) / 256, 256, 0, stream>>>(degs, nN);
        wp_kernel<<<(DDIM * DDIM + 255) / 256, 256, 0, stream>>>(W, lamda, layer, Wp);

        long long tot = (long long)nE * DDIM;
        int sblocks = (int)((tot + 255) / 256);
        scatter_kernel<<<sblocks, 256, 0, stream>>>(feat, degs, src, dst, out, nE);
        final_kernel<<<2048, 256, 0, stream>>>(out, feat0, degs, Wp, alpha, nN);
    }
}